// Round 6
// baseline (503.844 us; speedup 1.0000x reference)
//
#include <hip/hip_runtime.h>
#include <hip/hip_bf16.h>
#include <string.h>

#define NB   2
#define SEQ  2048
#define EMB  1024
#define NH   16
#define HD   64
// softmax uses exp2: fold SCALE*log2(e) into Q pre-scale and the mask table
#define QSCALE 0.045084219f       // (1/32) * log2(e)
#define MADD2  -4.5084219e18f     // -1e20 * (1/32) * log2(e)

typedef __attribute__((ext_vector_type(8))) short short8;   // 8 x bf16
typedef __attribute__((ext_vector_type(4))) float f32x4;    // MFMA C/D

#define MFMA(a, b, c) __builtin_amdgcn_mfma_f32_16x16x32_bf16(a, b, c, 0, 0, 0)
#define EXP2(x) __builtin_amdgcn_exp2f(x)

__device__ __forceinline__ unsigned short f2bf(float x) {
    union { float f; unsigned u; } v; v.f = x;
    unsigned r = v.u + 0x7fffu + ((v.u >> 16) & 1u);   // RNE
    return (unsigned short)(r >> 16);
}
__device__ __forceinline__ unsigned packbf2(float a, float b) {
    __hip_bfloat162 h = __float22bfloat162_rn(make_float2(a, b));  // hw v_cvt_pk
    unsigned u; memcpy(&u, &h, 4);
    return u;
}

// ---------------------------------------------------------------------------
// Kernel 0: convert Wo/Wq/Wk/Wv fp32->bf16, build exp2-domain madd table.
// ---------------------------------------------------------------------------
__global__ __launch_bounds__(256) void cvt_kernel(
    const float* __restrict__ Wo, const float* __restrict__ Wq,
    const float* __restrict__ Wk, const float* __restrict__ Wv,
    const int* __restrict__ mask,
    unsigned short* __restrict__ Wob, unsigned short* __restrict__ Wqb,
    unsigned short* __restrict__ Wkb, unsigned short* __restrict__ Wvb,
    float* __restrict__ maddG)
{
    const int b = blockIdx.x, tid = threadIdx.x;
    if (b < 1024) {                       // Wo: 262144 float4
        int idx = b * 256 + tid;
        float4 w = ((const float4*)Wo)[idx];
        uint2 p; p.x = packbf2(w.x, w.y); p.y = packbf2(w.z, w.w);
        ((uint2*)Wob)[idx] = p;
    } else if (b < 1027) {                // Wq/Wk/Wv: 1024 float4 each
        const float* W = (b == 1024) ? Wq : (b == 1025) ? Wk : Wv;
        unsigned short* Wb = (b == 1024) ? Wqb : (b == 1025) ? Wkb : Wvb;
        #pragma unroll
        for (int i = 0; i < 4; ++i) {
            int idx = tid + i * 256;
            float4 w = ((const float4*)W)[idx];
            uint2 p; p.x = packbf2(w.x, w.y); p.y = packbf2(w.z, w.w);
            ((uint2*)Wb)[idx] = p;
        }
    } else {                              // madd: NB*SEQ = 4096 entries
        #pragma unroll
        for (int i = 0; i < 16; ++i) {
            int idx = tid + i * 256;
            maddG[idx] = mask[idx] ? 0.f : MADD2;
        }
    }
}

// ---------------------------------------------------------------------------
// Kernel 1: per-head QKV projection.  grid (SEQ/128, NH, 3*NB), block 256.
// Q,K out: [n][h][l][d] bf16 (Q pre-scaled by QSCALE).  V out: [n][h][d][l].
// ---------------------------------------------------------------------------
__global__ __launch_bounds__(256) void qkv_kernel(
    const float* __restrict__ Qin, const float* __restrict__ Kin,
    const float* __restrict__ Vin,
    const unsigned short* __restrict__ Wqb, const unsigned short* __restrict__ Wkb,
    const unsigned short* __restrict__ Wvb, const float* __restrict__ bq,
    unsigned short* __restrict__ Qp, unsigned short* __restrict__ Kp,
    unsigned short* __restrict__ Vtp)
{
    const int lt = blockIdx.x;          // 128-row l tile
    const int h  = blockIdx.y;
    const int tz = blockIdx.z;
    const int t  = tz >> 1, n = tz & 1;

    const float* X; const unsigned short* Wb;
    if (t == 0)      { X = Qin; Wb = Wqb; }
    else if (t == 1) { X = Kin; Wb = Wkb; }
    else             { X = Vin; Wb = Wvb; }

    __shared__ __align__(16) unsigned short sX[128][70];
    __shared__ __align__(16) unsigned short sT[64][136];

    const int tid = threadIdx.x, wave = tid >> 6, lane = tid & 63;
    const int ln = lane & 15, quad = lane >> 4;

    #pragma unroll
    for (int i = 0; i < 8; ++i) {
        int flat = tid + i * 256;
        int r = flat >> 4, c4 = flat & 15;
        float4 xv = *(const float4*)(X + ((size_t)(n * SEQ + lt * 128 + r)) * EMB + h * HD + c4 * 4);
        uint2 xp; xp.x = packbf2(xv.x, xv.y); xp.y = packbf2(xv.z, xv.w);
        *(uint2*)&sX[r][c4 * 4] = xp;
    }
    short8 wf0[4], wf1[4];
    #pragma unroll
    for (int nt = 0; nt < 4; ++nt) {
        wf0[nt] = *(const short8*)(Wb + (nt * 16 + ln) * HD + quad * 8);
        wf1[nt] = *(const short8*)(Wb + (nt * 16 + ln) * HD + 32 + quad * 8);
    }
    __syncthreads();

    f32x4 acc[2][4];
    #pragma unroll
    for (int set = 0; set < 2; ++set) {
        short8 af0 = *(const short8*)&sX[wave * 32 + set * 16 + ln][quad * 8];
        short8 af1 = *(const short8*)&sX[wave * 32 + set * 16 + ln][32 + quad * 8];
        #pragma unroll
        for (int nt = 0; nt < 4; ++nt) {
            f32x4 a = {0.f, 0.f, 0.f, 0.f};
            a = MFMA(af0, wf0[nt], a);
            a = MFMA(af1, wf1[nt], a);
            acc[set][nt] = a;
        }
    }

    if (t == 0) {   // bias then fold softmax scale (incl. log2e)
        #pragma unroll
        for (int nt = 0; nt < 4; ++nt) {
            float bb = bq[nt * 16 + ln];
            #pragma unroll
            for (int set = 0; set < 2; ++set)
                #pragma unroll
                for (int a = 0; a < 4; ++a)
                    acc[set][nt][a] = (acc[set][nt][a] + bb) * QSCALE;
        }
    }

    if (t < 2) {
        unsigned short* Out = (t == 0) ? Qp : Kp;
        #pragma unroll
        for (int set = 0; set < 2; ++set)
            #pragma unroll
            for (int a = 0; a < 4; ++a) {
                size_t row = (size_t)((n * NH + h) * SEQ + lt * 128 + wave * 32 + set * 16 + quad * 4 + a);
                #pragma unroll
                for (int nt = 0; nt < 4; ++nt)
                    Out[row * HD + nt * 16 + ln] = f2bf(acc[set][nt][a]);
            }
    } else {
        #pragma unroll
        for (int set = 0; set < 2; ++set)
            #pragma unroll
            for (int nt = 0; nt < 4; ++nt)
                #pragma unroll
                for (int a = 0; a < 4; ++a)
                    sT[nt * 16 + ln][wave * 32 + set * 16 + quad * 4 + a] = f2bf(acc[set][nt][a]);
        __syncthreads();
        #pragma unroll
        for (int i = 0; i < 4; ++i) {
            int flat = tid + i * 256;
            int r = flat >> 4, c8 = flat & 15;
            *(float4*)(Vtp + ((size_t)((n * NH + h) * HD + r)) * SEQ + lt * 128 + c8 * 8) =
                *(const float4*)&sT[r][c8 * 8];
        }
    }
}

// ---------------------------------------------------------------------------
// Kernel 2: flash attention v6.  grid (NB*NH, SEQ/64), block 256 (4 waves).
// No K-loop barriers / staging: K/V fragments direct from global (L2-hot).
// 4-way in-block key split (exact: sum-softmax is a plain sum); each wave
// does 64 q-rows x 8 kt.  Pairwise fp32 combine through LDS at the end.
// ---------------------------------------------------------------------------
__global__ __launch_bounds__(256, 4) void flash_kernel(
    const unsigned short* __restrict__ Qp, const unsigned short* __restrict__ Kp,
    const unsigned short* __restrict__ Vtp, const float* __restrict__ maddG,
    unsigned short* __restrict__ A /* [n][l][EMB] bf16 */)
{
    const int nh = blockIdx.x;
    const int qt = blockIdx.y;
    const int n  = nh >> 4, h = nh & 15;

    const int tid  = threadIdx.x;
    const int wave = tid >> 6, lane = tid & 63;
    const int ln   = lane & 15, quad = lane >> 4;

    __shared__ __align__(16) unsigned short sP[4][64][72];   // per-wave P slices
    __shared__ float xl[4][64];
    // epilogue fp32 exchange overlays sP (dead after K-loop): 2 x 64x66 floats
    float (*xO0)[66] = reinterpret_cast<float(*)[66]>(&sP[0][0][0]);
    float (*xO1)[66] = reinterpret_cast<float(*)[66]>(
        reinterpret_cast<char*>(&sP[0][0][0]) + 64 * 66 * 4);

    // Q B-fragments for 4 row-sets (Q pre-scaled by QSCALE)
    const unsigned short* Qb = Qp + ((size_t)nh * SEQ + qt * 64) * HD;
    short8 qf[4][2];
    #pragma unroll
    for (int set = 0; set < 4; ++set) {
        qf[set][0] = *(const short8*)(Qb + (set * 16 + ln) * HD + quad * 8);
        qf[set][1] = *(const short8*)(Qb + (set * 16 + ln) * HD + 32 + quad * 8);
    }

    const unsigned short* Kb = Kp  + (size_t)nh * SEQ * HD;
    const unsigned short* Vb = Vtp + (size_t)nh * HD * SEQ;
    const float* mb = maddG + n * SEQ;

    f32x4 o[4][4];
    #pragma unroll
    for (int s2 = 0; s2 < 4; ++s2)
        #pragma unroll
        for (int dt = 0; dt < 4; ++dt) o[s2][dt] = (f32x4){0.f, 0.f, 0.f, 0.f};
    float lsum[4] = {0.f, 0.f, 0.f, 0.f};

    const int kt0 = wave * (SEQ / 64 / 4);          // 4-way in-block key split
    for (int kt = kt0; kt < kt0 + SEQ / 64 / 4; ++kt) {
        // V B-fragments direct from global (issued early, used after softmax)
        short8 vf[4][2];
        #pragma unroll
        for (int dt = 0; dt < 4; ++dt) {
            const unsigned short* vr = Vb + (size_t)(dt * 16 + ln) * SEQ + kt * 64;
            vf[dt][0] = *(const short8*)(vr + quad * 8);
            vf[dt][1] = *(const short8*)(vr + 32 + quad * 8);
        }

        #pragma unroll
        for (int nt = 0; nt < 4; ++nt) {
            // K A-fragments direct from global
            const unsigned short* kr = Kb + (size_t)(kt * 64 + nt * 16 + ln) * HD;
            short8 kf0 = *(const short8*)(kr + quad * 8);
            short8 kf1 = *(const short8*)(kr + 32 + quad * 8);
            float4 md  = *(const float4*)(mb + kt * 64 + nt * 16 + quad * 4);

            #pragma unroll
            for (int set = 0; set < 4; ++set) {
                f32x4 z = {0.f, 0.f, 0.f, 0.f};
                z = MFMA(kf0, qf[set][0], z);
                z = MFMA(kf1, qf[set][1], z);
                // S^T C-layout: (key = nt*16+quad*4+a, q = set*16+ln)
                // no clamp: |scores| << 128 in exp2 domain; masked -> exp2(-inf)=0
                float p0 = EXP2(z[0] + md.x);
                float p1 = EXP2(z[1] + md.y);
                float p2 = EXP2(z[2] + md.z);
                float p3 = EXP2(z[3] + md.w);
                lsum[set] += (p0 + p1) + (p2 + p3);
                uint2 w; w.x = packbf2(p0, p1); w.y = packbf2(p2, p3);
                *(uint2*)&sP[wave][set * 16 + ln][nt * 16 + quad * 4] = w;
            }
        }
        asm volatile("s_waitcnt lgkmcnt(0)" ::: "memory");   // per-wave slice

        // ---- O += P V ----
        #pragma unroll
        for (int set = 0; set < 4; ++set) {
            short8 pf0 = *(const short8*)&sP[wave][set * 16 + ln][quad * 8];
            short8 pf1 = *(const short8*)&sP[wave][set * 16 + ln][32 + quad * 8];
            #pragma unroll
            for (int dt = 0; dt < 4; ++dt) {
                o[set][dt] = MFMA(pf0, vf[dt][0], o[set][dt]);
                o[set][dt] = MFMA(pf1, vf[dt][1], o[set][dt]);
            }
        }
    }

    // ---- reduce l over quads (uniform across lanes for q = set*16+ln) ----
    float lf[4];
    #pragma unroll
    for (int set = 0; set < 4; ++set) {
        float l = lsum[set];
        l += __shfl_xor(l, 16);
        l += __shfl_xor(l, 32);
        lf[set] = l;
    }
    if (quad == 0) {
        #pragma unroll
        for (int set = 0; set < 4; ++set) xl[wave][set * 16 + ln] = lf[set];
    }

    // ---- pairwise combine of the 4 key-quarters (fp32, exact reorder) ----
    __syncthreads();                      // all waves done with sP
    if (wave & 1) {                       // waves 1,3 dump
        float (*xO)[66] = (wave == 1) ? xO0 : xO1;
        #pragma unroll
        for (int set = 0; set < 4; ++set)
            #pragma unroll
            for (int a = 0; a < 4; ++a)
                #pragma unroll
                for (int dt = 0; dt < 4; ++dt)
                    xO[set * 16 + quad * 4 + a][dt * 16 + ln] = o[set][dt][a];
    }
    __syncthreads();
    if (!(wave & 1)) {                    // waves 0,2 accumulate partner
        float (*xO)[66] = (wave == 0) ? xO0 : xO1;
        #pragma unroll
        for (int set = 0; set < 4; ++set)
            #pragma unroll
            for (int a = 0; a < 4; ++a)
                #pragma unroll
                for (int dt = 0; dt < 4; ++dt)
                    o[set][dt][a] += xO[set * 16 + quad * 4 + a][dt * 16 + ln];
    }
    __syncthreads();
    if (wave == 2) {                      // dump half-sum
        #pragma unroll
        for (int set = 0; set < 4; ++set)
            #pragma unroll
            for (int a = 0; a < 4; ++a)
                #pragma unroll
                for (int dt = 0; dt < 4; ++dt)
                    xO0[set * 16 + quad * 4 + a][dt * 16 + ln] = o[set][dt][a];
    }
    __syncthreads();
    if (wave == 0) {                      // final sum + normalize + store
        #pragma unroll
        for (int set = 0; set < 4; ++set) {
            float lfull = xl[0][set * 16 + ln] + xl[1][set * 16 + ln] +
                          xl[2][set * 16 + ln] + xl[3][set * 16 + ln];
            #pragma unroll
            for (int a = 0; a < 4; ++a) {
                int q = set * 16 + quad * 4 + a;
                float inv = 1.0f / __shfl(lfull, quad * 4 + a);
                size_t row = (size_t)(n * SEQ + qt * 64 + q);
                #pragma unroll
                for (int dt = 0; dt < 4; ++dt)
                    A[row * EMB + h * HD + dt * 16 + ln] =
                        f2bf((o[set][dt][a] + xO0[q][dt * 16 + ln]) * inv);
            }
        }
    }
}

// ---------------------------------------------------------------------------
// Kernel 3: out = A @ Wo^T + bo — LDS-free, barrier-free direct-fragment GEMM.
// 1024 wave-tiles of 64x64; grid 256 x 256 (4 independent waves per block).
// A (bf16, k-contig) and Wo (bf16, k-contig) load straight into frag layout.
// ---------------------------------------------------------------------------
__global__ __launch_bounds__(256) void outproj_kernel(
    const unsigned short* __restrict__ A, const unsigned short* __restrict__ Wob,
    const float* __restrict__ bo, float* __restrict__ Out)
{
    const int tid = threadIdx.x, wave = tid >> 6, lane = tid & 63;
    const int ln = lane & 15, quad = lane >> 4;
    const int id = blockIdx.x * 4 + wave;      // 0..1023
    const int mt = id >> 4, nt4 = id & 15;     // 64 m-tiles x 16 n-tiles

    const unsigned short* Ab = A   + (size_t)(mt * 64) * EMB;
    const unsigned short* Bb = Wob + (size_t)(nt4 * 64) * EMB;

    f32x4 acc[4][4];
    #pragma unroll
    for (int i = 0; i < 4; ++i)
        #pragma unroll
        for (int j = 0; j < 4; ++j) acc[i][j] = (f32x4){0.f, 0.f, 0.f, 0.f};

    for (int ks = 0; ks < EMB / 32; ++ks) {
        short8 af[4], bf[4];
        #pragma unroll
        for (int i = 0; i < 4; ++i)
            af[i] = *(const short8*)(Ab + (size_t)(i * 16 + ln) * EMB + ks * 32 + quad * 8);
        #pragma unroll
        for (int j = 0; j < 4; ++j)
            bf[j] = *(const short8*)(Bb + (size_t)(j * 16 + ln) * EMB + ks * 32 + quad * 8);
        #pragma unroll
        for (int i = 0; i < 4; ++i)
            #pragma unroll
            for (int j = 0; j < 4; ++j)
                acc[i][j] = MFMA(af[i], bf[j], acc[i][j]);
    }

    #pragma unroll
    for (int j = 0; j < 4; ++j) {
        int col = nt4 * 64 + j * 16 + ln;
        float bb = bo[col];
        #pragma unroll
        for (int i = 0; i < 4; ++i)
            #pragma unroll
            for (int a = 0; a < 4; ++a) {
                size_t row = (size_t)(mt * 64 + i * 16 + quad * 4 + a);
                Out[row * EMB + col] = acc[i][j][a] + bb;
            }
    }
}

// ---------------------------------------------------------------------------
extern "C" void kernel_launch(void* const* d_in, const int* in_sizes, int n_in,
                              void* d_out, int out_size, void* d_ws, size_t ws_size,
                              hipStream_t stream) {
    const float* values = (const float*)d_in[0];
    const float* key_   = (const float*)d_in[1];
    const float* query  = (const float*)d_in[2];
    const int*   mask   = (const int*)d_in[3];
    const float* Wv     = (const float*)d_in[4];
    const float* Wk     = (const float*)d_in[5];
    const float* Wq     = (const float*)d_in[6];
    const float* bq     = (const float*)d_in[7];
    const float* Wo     = (const float*)d_in[8];
    const float* bo     = (const float*)d_in[9];
    float* out = (float*)d_out;

    const size_t NHLD = (size_t)NB * NH * SEQ * HD;   // 4,194,304

    unsigned short* ws = (unsigned short*)d_ws;
    unsigned short* Qp    = ws;
    unsigned short* Kp    = ws + NHLD;
    unsigned short* Vtp   = ws + 2 * NHLD;
    unsigned short* Aattn = ws + 3 * NHLD;
    unsigned short* Wob   = ws + 4 * NHLD;                  // EMB*EMB
    unsigned short* Wqb   = Wob + (size_t)EMB * EMB;
    unsigned short* Wkb   = Wqb + HD * HD;
    unsigned short* Wvb   = Wkb + HD * HD;
    float* maddG = (float*)(Wvb + HD * HD);                 // NB*SEQ floats

    cvt_kernel<<<dim3(1028), 256, 0, stream>>>(
        Wo, Wq, Wk, Wv, mask, Wob, Wqb, Wkb, Wvb, maddG);
    qkv_kernel<<<dim3(SEQ / 128, NH, 3 * NB), 256, 0, stream>>>(
        query, key_, values, Wqb, Wkb, Wvb, bq, Qp, Kp, Vtp);
    flash_kernel<<<dim3(NB * NH, SEQ / 64), 256, 0, stream>>>(
        Qp, Kp, Vtp, maddG, Aattn);
    outproj_kernel<<<dim3(256), 256, 0, stream>>>(
        Aattn, Wob, bo, out);
}

// Round 7
// 233.625 us; speedup vs baseline: 2.1566x; 2.1566x over previous
//
#include <hip/hip_runtime.h>
#include <hip/hip_bf16.h>
#include <string.h>

#define NB   2
#define SEQ  2048
#define EMB  1024
#define NH   16
#define HD   64
// softmax uses exp2: fold SCALE*log2(e) into Q pre-scale and the mask table
#define QSCALE 0.045084219f       // (1/32) * log2(e)
#define MADD2  -4.5084219e18f     // -1e20 * (1/32) * log2(e)

typedef __attribute__((ext_vector_type(8))) short short8;   // 8 x bf16
typedef __attribute__((ext_vector_type(4))) float f32x4;    // MFMA C/D

#define MFMA(a, b, c) __builtin_amdgcn_mfma_f32_16x16x32_bf16(a, b, c, 0, 0, 0)
#define EXP2(x) __builtin_amdgcn_exp2f(x)

__device__ __forceinline__ unsigned short f2bf(float x) {
    union { float f; unsigned u; } v; v.f = x;
    unsigned r = v.u + 0x7fffu + ((v.u >> 16) & 1u);   // RNE
    return (unsigned short)(r >> 16);
}
__device__ __forceinline__ unsigned packbf2(float a, float b) {
    __hip_bfloat162 h = __float22bfloat162_rn(make_float2(a, b));  // hw v_cvt_pk
    unsigned u; memcpy(&u, &h, 4);
    return u;
}

// ---------------------------------------------------------------------------
// Kernel 0: convert Wo/Wq/Wk/Wv fp32->bf16, build exp2-domain madd table.
// ---------------------------------------------------------------------------
__global__ __launch_bounds__(256) void cvt_kernel(
    const float* __restrict__ Wo, const float* __restrict__ Wq,
    const float* __restrict__ Wk, const float* __restrict__ Wv,
    const int* __restrict__ mask,
    unsigned short* __restrict__ Wob, unsigned short* __restrict__ Wqb,
    unsigned short* __restrict__ Wkb, unsigned short* __restrict__ Wvb,
    float* __restrict__ maddG)
{
    const int b = blockIdx.x, tid = threadIdx.x;
    if (b < 1024) {                       // Wo: 262144 float4
        int idx = b * 256 + tid;
        float4 w = ((const float4*)Wo)[idx];
        uint2 p; p.x = packbf2(w.x, w.y); p.y = packbf2(w.z, w.w);
        ((uint2*)Wob)[idx] = p;
    } else if (b < 1027) {                // Wq/Wk/Wv: 1024 float4 each
        const float* W = (b == 1024) ? Wq : (b == 1025) ? Wk : Wv;
        unsigned short* Wb = (b == 1024) ? Wqb : (b == 1025) ? Wkb : Wvb;
        #pragma unroll
        for (int i = 0; i < 4; ++i) {
            int idx = tid + i * 256;
            float4 w = ((const float4*)W)[idx];
            uint2 p; p.x = packbf2(w.x, w.y); p.y = packbf2(w.z, w.w);
            ((uint2*)Wb)[idx] = p;
        }
    } else {                              // madd: NB*SEQ = 4096 entries
        #pragma unroll
        for (int i = 0; i < 16; ++i) {
            int idx = tid + i * 256;
            maddG[idx] = mask[idx] ? 0.f : MADD2;
        }
    }
}

// ---------------------------------------------------------------------------
// Kernel 1: per-head QKV projection.  grid (SEQ/128, NH, 3*NB), block 256.
// Q,K out: [n][h][l][d] bf16 (Q pre-scaled by QSCALE).  V out: [n][h][d][l].
// ---------------------------------------------------------------------------
__global__ __launch_bounds__(256) void qkv_kernel(
    const float* __restrict__ Qin, const float* __restrict__ Kin,
    const float* __restrict__ Vin,
    const unsigned short* __restrict__ Wqb, const unsigned short* __restrict__ Wkb,
    const unsigned short* __restrict__ Wvb, const float* __restrict__ bq,
    unsigned short* __restrict__ Qp, unsigned short* __restrict__ Kp,
    unsigned short* __restrict__ Vtp)
{
    const int lt = blockIdx.x;          // 128-row l tile
    const int h  = blockIdx.y;
    const int tz = blockIdx.z;
    const int t  = tz >> 1, n = tz & 1;

    const float* X; const unsigned short* Wb;
    if (t == 0)      { X = Qin; Wb = Wqb; }
    else if (t == 1) { X = Kin; Wb = Wkb; }
    else             { X = Vin; Wb = Wvb; }

    __shared__ __align__(16) unsigned short sX[128][70];
    __shared__ __align__(16) unsigned short sT[64][136];

    const int tid = threadIdx.x, wave = tid >> 6, lane = tid & 63;
    const int ln = lane & 15, quad = lane >> 4;

    #pragma unroll
    for (int i = 0; i < 8; ++i) {
        int flat = tid + i * 256;
        int r = flat >> 4, c4 = flat & 15;
        float4 xv = *(const float4*)(X + ((size_t)(n * SEQ + lt * 128 + r)) * EMB + h * HD + c4 * 4);
        uint2 xp; xp.x = packbf2(xv.x, xv.y); xp.y = packbf2(xv.z, xv.w);
        *(uint2*)&sX[r][c4 * 4] = xp;
    }
    short8 wf0[4], wf1[4];
    #pragma unroll
    for (int nt = 0; nt < 4; ++nt) {
        wf0[nt] = *(const short8*)(Wb + (nt * 16 + ln) * HD + quad * 8);
        wf1[nt] = *(const short8*)(Wb + (nt * 16 + ln) * HD + 32 + quad * 8);
    }
    __syncthreads();

    f32x4 acc[2][4];
    #pragma unroll
    for (int set = 0; set < 2; ++set) {
        short8 af0 = *(const short8*)&sX[wave * 32 + set * 16 + ln][quad * 8];
        short8 af1 = *(const short8*)&sX[wave * 32 + set * 16 + ln][32 + quad * 8];
        #pragma unroll
        for (int nt = 0; nt < 4; ++nt) {
            f32x4 a = {0.f, 0.f, 0.f, 0.f};
            a = MFMA(af0, wf0[nt], a);
            a = MFMA(af1, wf1[nt], a);
            acc[set][nt] = a;
        }
    }

    if (t == 0) {   // bias then fold softmax scale (incl. log2e)
        #pragma unroll
        for (int nt = 0; nt < 4; ++nt) {
            float bb = bq[nt * 16 + ln];
            #pragma unroll
            for (int set = 0; set < 2; ++set)
                #pragma unroll
                for (int a = 0; a < 4; ++a)
                    acc[set][nt][a] = (acc[set][nt][a] + bb) * QSCALE;
        }
    }

    if (t < 2) {
        unsigned short* Out = (t == 0) ? Qp : Kp;
        #pragma unroll
        for (int set = 0; set < 2; ++set)
            #pragma unroll
            for (int a = 0; a < 4; ++a) {
                size_t row = (size_t)((n * NH + h) * SEQ + lt * 128 + wave * 32 + set * 16 + quad * 4 + a);
                #pragma unroll
                for (int nt = 0; nt < 4; ++nt)
                    Out[row * HD + nt * 16 + ln] = f2bf(acc[set][nt][a]);
            }
    } else {
        #pragma unroll
        for (int set = 0; set < 2; ++set)
            #pragma unroll
            for (int nt = 0; nt < 4; ++nt)
                #pragma unroll
                for (int a = 0; a < 4; ++a)
                    sT[nt * 16 + ln][wave * 32 + set * 16 + quad * 4 + a] = f2bf(acc[set][nt][a]);
        __syncthreads();
        #pragma unroll
        for (int i = 0; i < 4; ++i) {
            int flat = tid + i * 256;
            int r = flat >> 4, c8 = flat & 15;
            *(float4*)(Vtp + ((size_t)((n * NH + h) * HD + r)) * SEQ + lt * 128 + c8 * 8) =
                *(const float4*)&sT[r][c8 * 8];
        }
    }
}

// ---------------------------------------------------------------------------
// Kernel 2: flash attention v7.  grid (NB*NH, SEQ/64), block 256 (4 waves).
// No K-loop barriers / staging: K/V fragments direct from global (L2-hot).
// 4-way in-block key split (exact: sum-softmax is a plain sum); each wave
// does 64 q-rows x 8 kt.  Pairwise fp32 combine through LDS at the end.
// NOTE: no min-wave launch bound — forcing 4/EU drove VGPR to 64 and spilled
// ~1.6 GB/launch to scratch (R6: WRITE_SIZE 960 MB, 352 us).  Allocator needs
// ~150 VGPRs (o=64, qf=32, vf=32 transient).
// ---------------------------------------------------------------------------
__global__ __launch_bounds__(256) void flash_kernel(
    const unsigned short* __restrict__ Qp, const unsigned short* __restrict__ Kp,
    const unsigned short* __restrict__ Vtp, const float* __restrict__ maddG,
    unsigned short* __restrict__ A /* [n][l][EMB] bf16 */)
{
    const int nh = blockIdx.x;
    const int qt = blockIdx.y;
    const int n  = nh >> 4, h = nh & 15;

    const int tid  = threadIdx.x;
    const int wave = tid >> 6, lane = tid & 63;
    const int ln   = lane & 15, quad = lane >> 4;

    __shared__ __align__(16) unsigned short sP[4][64][72];   // per-wave P slices
    __shared__ float xl[4][64];
    // epilogue fp32 exchange overlays sP (dead after K-loop): 2 x 64x66 floats
    float (*xO0)[66] = reinterpret_cast<float(*)[66]>(&sP[0][0][0]);
    float (*xO1)[66] = reinterpret_cast<float(*)[66]>(
        reinterpret_cast<char*>(&sP[0][0][0]) + 64 * 66 * 4);

    // Q B-fragments for 4 row-sets (Q pre-scaled by QSCALE)
    const unsigned short* Qb = Qp + ((size_t)nh * SEQ + qt * 64) * HD;
    short8 qf[4][2];
    #pragma unroll
    for (int set = 0; set < 4; ++set) {
        qf[set][0] = *(const short8*)(Qb + (set * 16 + ln) * HD + quad * 8);
        qf[set][1] = *(const short8*)(Qb + (set * 16 + ln) * HD + 32 + quad * 8);
    }

    const unsigned short* Kb = Kp  + (size_t)nh * SEQ * HD;
    const unsigned short* Vb = Vtp + (size_t)nh * HD * SEQ;
    const float* mb = maddG + n * SEQ;

    f32x4 o[4][4];
    #pragma unroll
    for (int s2 = 0; s2 < 4; ++s2)
        #pragma unroll
        for (int dt = 0; dt < 4; ++dt) o[s2][dt] = (f32x4){0.f, 0.f, 0.f, 0.f};
    float lsum[4] = {0.f, 0.f, 0.f, 0.f};

    const int kt0 = wave * (SEQ / 64 / 4);          // 4-way in-block key split
    for (int kt = kt0; kt < kt0 + SEQ / 64 / 4; ++kt) {
        #pragma unroll
        for (int nt = 0; nt < 4; ++nt) {
            // K A-fragments direct from global
            const unsigned short* kr = Kb + (size_t)(kt * 64 + nt * 16 + ln) * HD;
            short8 kf0 = *(const short8*)(kr + quad * 8);
            short8 kf1 = *(const short8*)(kr + 32 + quad * 8);
            float4 md  = *(const float4*)(mb + kt * 64 + nt * 16 + quad * 4);

            #pragma unroll
            for (int set = 0; set < 4; ++set) {
                f32x4 z = {0.f, 0.f, 0.f, 0.f};
                z = MFMA(kf0, qf[set][0], z);
                z = MFMA(kf1, qf[set][1], z);
                // S^T C-layout: (key = nt*16+quad*4+a, q = set*16+ln)
                // no clamp: |scores| << 128 in exp2 domain; masked -> exp2(-inf)=0
                float p0 = EXP2(z[0] + md.x);
                float p1 = EXP2(z[1] + md.y);
                float p2 = EXP2(z[2] + md.z);
                float p3 = EXP2(z[3] + md.w);
                lsum[set] += (p0 + p1) + (p2 + p3);
                uint2 w; w.x = packbf2(p0, p1); w.y = packbf2(p2, p3);
                *(uint2*)&sP[wave][set * 16 + ln][nt * 16 + quad * 4] = w;
            }
        }

        // V B-fragments from global (L2-hit; loaded late = short live range)
        short8 vf[4][2];
        #pragma unroll
        for (int dt = 0; dt < 4; ++dt) {
            const unsigned short* vr = Vb + (size_t)(dt * 16 + ln) * SEQ + kt * 64;
            vf[dt][0] = *(const short8*)(vr + quad * 8);
            vf[dt][1] = *(const short8*)(vr + 32 + quad * 8);
        }
        asm volatile("s_waitcnt lgkmcnt(0)" ::: "memory");   // per-wave slice

        // ---- O += P V ----
        #pragma unroll
        for (int set = 0; set < 4; ++set) {
            short8 pf0 = *(const short8*)&sP[wave][set * 16 + ln][quad * 8];
            short8 pf1 = *(const short8*)&sP[wave][set * 16 + ln][32 + quad * 8];
            #pragma unroll
            for (int dt = 0; dt < 4; ++dt) {
                o[set][dt] = MFMA(pf0, vf[dt][0], o[set][dt]);
                o[set][dt] = MFMA(pf1, vf[dt][1], o[set][dt]);
            }
        }
    }

    // ---- reduce l over quads (uniform across lanes for q = set*16+ln) ----
    float lf[4];
    #pragma unroll
    for (int set = 0; set < 4; ++set) {
        float l = lsum[set];
        l += __shfl_xor(l, 16);
        l += __shfl_xor(l, 32);
        lf[set] = l;
    }
    if (quad == 0) {
        #pragma unroll
        for (int set = 0; set < 4; ++set) xl[wave][set * 16 + ln] = lf[set];
    }

    // ---- pairwise combine of the 4 key-quarters (fp32, exact reorder) ----
    __syncthreads();                      // all waves done with sP
    if (wave & 1) {                       // waves 1,3 dump
        float (*xO)[66] = (wave == 1) ? xO0 : xO1;
        #pragma unroll
        for (int set = 0; set < 4; ++set)
            #pragma unroll
            for (int a = 0; a < 4; ++a)
                #pragma unroll
                for (int dt = 0; dt < 4; ++dt)
                    xO[set * 16 + quad * 4 + a][dt * 16 + ln] = o[set][dt][a];
    }
    __syncthreads();
    if (!(wave & 1)) {                    // waves 0,2 accumulate partner
        float (*xO)[66] = (wave == 0) ? xO0 : xO1;
        #pragma unroll
        for (int set = 0; set < 4; ++set)
            #pragma unroll
            for (int a = 0; a < 4; ++a)
                #pragma unroll
                for (int dt = 0; dt < 4; ++dt)
                    o[set][dt][a] += xO[set * 16 + quad * 4 + a][dt * 16 + ln];
    }
    __syncthreads();
    if (wave == 2) {                      // dump half-sum
        #pragma unroll
        for (int set = 0; set < 4; ++set)
            #pragma unroll
            for (int a = 0; a < 4; ++a)
                #pragma unroll
                for (int dt = 0; dt < 4; ++dt)
                    xO0[set * 16 + quad * 4 + a][dt * 16 + ln] = o[set][dt][a];
    }
    __syncthreads();
    if (wave == 0) {                      // final sum + normalize + store
        #pragma unroll
        for (int set = 0; set < 4; ++set) {
            float lfull = xl[0][set * 16 + ln] + xl[1][set * 16 + ln] +
                          xl[2][set * 16 + ln] + xl[3][set * 16 + ln];
            #pragma unroll
            for (int a = 0; a < 4; ++a) {
                int q = set * 16 + quad * 4 + a;
                float inv = 1.0f / __shfl(lfull, quad * 4 + a);
                size_t row = (size_t)(n * SEQ + qt * 64 + q);
                #pragma unroll
                for (int dt = 0; dt < 4; ++dt)
                    A[row * EMB + h * HD + dt * 16 + ln] =
                        f2bf((o[set][dt][a] + xO0[q][dt * 16 + ln]) * inv);
            }
        }
    }
}

// ---------------------------------------------------------------------------
// Kernel 3: out = A @ Wo^T + bo — LDS-free, barrier-free direct-fragment GEMM.
// 1024 wave-tiles of 64x64; grid 512 x 128 (2 tiles/block -> 2 blocks/CU).
// ---------------------------------------------------------------------------
__global__ __launch_bounds__(128) void outproj_kernel(
    const unsigned short* __restrict__ A, const unsigned short* __restrict__ Wob,
    const float* __restrict__ bo, float* __restrict__ Out)
{
    const int tid = threadIdx.x, wave = tid >> 6, lane = tid & 63;
    const int ln = lane & 15, quad = lane >> 4;
    const int id = blockIdx.x * 2 + wave;      // 0..1023
    const int mt = id >> 4, nt4 = id & 15;     // 64 m-tiles x 16 n-tiles

    const unsigned short* Ab = A   + (size_t)(mt * 64) * EMB;
    const unsigned short* Bb = Wob + (size_t)(nt4 * 64) * EMB;

    f32x4 acc[4][4];
    #pragma unroll
    for (int i = 0; i < 4; ++i)
        #pragma unroll
        for (int j = 0; j < 4; ++j) acc[i][j] = (f32x4){0.f, 0.f, 0.f, 0.f};

    for (int ks = 0; ks < EMB / 32; ++ks) {
        short8 af[4], bf[4];
        #pragma unroll
        for (int i = 0; i < 4; ++i)
            af[i] = *(const short8*)(Ab + (size_t)(i * 16 + ln) * EMB + ks * 32 + quad * 8);
        #pragma unroll
        for (int j = 0; j < 4; ++j)
            bf[j] = *(const short8*)(Bb + (size_t)(j * 16 + ln) * EMB + ks * 32 + quad * 8);
        #pragma unroll
        for (int i = 0; i < 4; ++i)
            #pragma unroll
            for (int j = 0; j < 4; ++j)
                acc[i][j] = MFMA(af[i], bf[j], acc[i][j]);
    }

    #pragma unroll
    for (int j = 0; j < 4; ++j) {
        int col = nt4 * 64 + j * 16 + ln;
        float bb = bo[col];
        #pragma unroll
        for (int i = 0; i < 4; ++i)
            #pragma unroll
            for (int a = 0; a < 4; ++a) {
                size_t row = (size_t)(mt * 64 + i * 16 + quad * 4 + a);
                Out[row * EMB + col] = acc[i][j][a] + bb;
            }
    }
}

// ---------------------------------------------------------------------------
extern "C" void kernel_launch(void* const* d_in, const int* in_sizes, int n_in,
                              void* d_out, int out_size, void* d_ws, size_t ws_size,
                              hipStream_t stream) {
    const float* values = (const float*)d_in[0];
    const float* key_   = (const float*)d_in[1];
    const float* query  = (const float*)d_in[2];
    const int*   mask   = (const int*)d_in[3];
    const float* Wv     = (const float*)d_in[4];
    const float* Wk     = (const float*)d_in[5];
    const float* Wq     = (const float*)d_in[6];
    const float* bq     = (const float*)d_in[7];
    const float* Wo     = (const float*)d_in[8];
    const float* bo     = (const float*)d_in[9];
    float* out = (float*)d_out;

    const size_t NHLD = (size_t)NB * NH * SEQ * HD;   // 4,194,304

    unsigned short* ws = (unsigned short*)d_ws;
    unsigned short* Qp    = ws;
    unsigned short* Kp    = ws + NHLD;
    unsigned short* Vtp   = ws + 2 * NHLD;
    unsigned short* Aattn = ws + 3 * NHLD;
    unsigned short* Wob   = ws + 4 * NHLD;                  // EMB*EMB
    unsigned short* Wqb   = Wob + (size_t)EMB * EMB;
    unsigned short* Wkb   = Wqb + HD * HD;
    unsigned short* Wvb   = Wkb + HD * HD;
    float* maddG = (float*)(Wvb + HD * HD);                 // NB*SEQ floats

    cvt_kernel<<<dim3(1028), 256, 0, stream>>>(
        Wo, Wq, Wk, Wv, mask, Wob, Wqb, Wkb, Wvb, maddG);
    qkv_kernel<<<dim3(SEQ / 128, NH, 3 * NB), 256, 0, stream>>>(
        query, key_, values, Wqb, Wkb, Wvb, bq, Qp, Kp, Vtp);
    flash_kernel<<<dim3(NB * NH, SEQ / 64), 256, 0, stream>>>(
        Qp, Kp, Vtp, maddG, Aattn);
    outproj_kernel<<<dim3(512), 128, 0, stream>>>(
        Aattn, Wob, bo, out);
}